// Round 3
// baseline (344.840 us; speedup 1.0000x reference)
//
#include <hip/hip_runtime.h>

typedef unsigned short u16;
typedef unsigned int   u32;
typedef __bf16 bf16x8 __attribute__((ext_vector_type(8)));
typedef float  f32x4  __attribute__((ext_vector_type(4)));

#define NTOK   8192
#define NSLOT  16384

// ---- workspace layout (bytes) ----
#define XB_OFF   0UL           // x as bf16 [8192][1024]            16 MB
#define WIT_OFF  16777216UL    // wi^T bf16 [8][1024 d][1024 h]     16 MB
#define WOT_OFF  33554432UL    // wo^T bf16 [8][1024 o][1024 d]     16 MB
#define HB_OFF   50331648UL    // H bf16 [16384][1024]              32 MB
#define RE_OFF   83886080UL    // route_e int[16384]
#define RP_OFF   83951616UL    // route_p float[16384]
#define SEG_OFF  84017152UL    // seg int[16384]
#define META_OFF 84082688UL
// META: counts[8]@0, offs[9]@64, cursors[8]@128, ntiles@192, zsum@196,
//       tile_e[72]@256, tile_r0[72]@1024
#define WS_NEED  (META_OFF + 2048UL)

__device__ __forceinline__ u16 f2b(float f) {
  u32 u = __float_as_uint(f);
  u32 r = (u + 0x7fffu + ((u >> 16) & 1u)) >> 16;   // RNE
  return (u16)r;
}

__device__ __forceinline__ void async_cp16(const void* g, void* l) {
  __builtin_amdgcn_global_load_lds(
      (const __attribute__((address_space(1))) u32*)g,
      (__attribute__((address_space(3))) u32*)l, 16, 0, 0);
}

__device__ __forceinline__ float gelu_f(float v) {
  float u  = 0.7978845608028654f * (v + 0.044715f * v * v * v);
  float ex = __expf(2.0f * u);
  float th = 1.0f - 2.0f / (ex + 1.0f);
  return 0.5f * v * (1.0f + th);
}

// ---------- transpose fp32 [1024][1024] -> bf16 ^T, both weight tensors ----------
__global__ __launch_bounds__(256) void k_transpose(const float* __restrict__ wi,
                                                   const float* __restrict__ wo,
                                                   u16* __restrict__ wit,
                                                   u16* __restrict__ wot) {
  __shared__ float t[64][65];
  int z = blockIdx.z;
  int e = z & 7;
  const float* src = ((z < 8) ? wi : wo) + ((size_t)e << 20);
  u16* dst = ((z < 8) ? wit : wot) + ((size_t)e << 20);
  int h0 = blockIdx.y * 64, d0 = blockIdx.x * 64;
  int tid = threadIdx.x;
#pragma unroll
  for (int j = 0; j < 4; j++) {
    int f = tid + 256 * j;
    int r = f >> 4, c4 = f & 15;
    float4 v = *(const float4*)&src[(size_t)(h0 + r) * 1024 + d0 + c4 * 4];
    t[r][c4 * 4 + 0] = v.x; t[r][c4 * 4 + 1] = v.y;
    t[r][c4 * 4 + 2] = v.z; t[r][c4 * 4 + 3] = v.w;
  }
  __syncthreads();
#pragma unroll
  for (int j = 0; j < 4; j++) {
    int f = tid + 256 * j;
    int d = f >> 4, c4 = f & 15;
    u32 p0 = (u32)f2b(t[c4 * 4 + 0][d]) | ((u32)f2b(t[c4 * 4 + 1][d]) << 16);
    u32 p1 = (u32)f2b(t[c4 * 4 + 2][d]) | ((u32)f2b(t[c4 * 4 + 3][d]) << 16);
    u32* dp = (u32*)&dst[(size_t)(d0 + d) * 1024 + h0 + c4 * 4];
    dp[0] = p0; dp[1] = p1;
  }
}

// ---------- router: logits, softmax, top2, z-loss, counts; also emits xb ----------
__global__ __launch_bounds__(256) void k_router(const float* __restrict__ x,
    const float* __restrict__ rw, const float* __restrict__ rb,
    u16* __restrict__ xb, int* __restrict__ route_e, float* __restrict__ route_p,
    int* __restrict__ counts, float* __restrict__ zsum) {
  __shared__ float lx[32][257];
  __shared__ float lrw[1024 * 9];
  __shared__ float llog[32 * 9];
  int tid = threadIdx.x;
  int t0  = blockIdx.x * 32;
#pragma unroll
  for (int j = 0; j < 8; j++) {
    int f = tid + 256 * j;
    int h = f >> 1, half = f & 1;
    float4 v = *(const float4*)&rw[h * 8 + half * 4];
    lrw[h * 9 + half * 4 + 0] = v.x; lrw[h * 9 + half * 4 + 1] = v.y;
    lrw[h * 9 + half * 4 + 2] = v.z; lrw[h * 9 + half * 4 + 3] = v.w;
  }
  int tl = tid & 31, e = tid >> 5;
  float acc = rb[e];
  for (int ch = 0; ch < 4; ch++) {
    __syncthreads();
#pragma unroll
    for (int j = 0; j < 8; j++) {
      int f = tid + 256 * j;
      int r = f >> 6, c4 = f & 63;
      float4 v = *(const float4*)&x[(size_t)(t0 + r) * 1024 + ch * 256 + c4 * 4];
      lx[r][c4 * 4 + 0] = v.x; lx[r][c4 * 4 + 1] = v.y;
      lx[r][c4 * 4 + 2] = v.z; lx[r][c4 * 4 + 3] = v.w;
    }
    __syncthreads();
    for (int hl = 0; hl < 256; hl++)
      acc += lx[tl][hl] * lrw[(ch * 256 + hl) * 9 + e];
#pragma unroll
    for (int j = 0; j < 16; j++) {
      int f = tid + 256 * j;
      int r = f >> 7, cp = f & 127;
      u32 pk = (u32)f2b(lx[r][cp * 2]) | ((u32)f2b(lx[r][cp * 2 + 1]) << 16);
      *(u32*)&xb[(size_t)(t0 + r) * 1024 + ch * 256 + cp * 2] = pk;
    }
  }
  llog[tl * 9 + e] = acc;
  __syncthreads();
  if (tid < 32) {
    int t = t0 + tid;
    float lg[8];
#pragma unroll
    for (int k = 0; k < 8; k++) lg[k] = llog[tid * 9 + k];
    int e0 = 0; float b0 = lg[0];
#pragma unroll
    for (int k = 1; k < 8; k++) if (lg[k] > b0) { b0 = lg[k]; e0 = k; }
    int e1 = -1; float b1 = -3.4e38f;
#pragma unroll
    for (int k = 0; k < 8; k++) { if (k == e0) continue; if (lg[k] > b1) { b1 = lg[k]; e1 = k; } }
    float s = 0.f;
#pragma unroll
    for (int k = 0; k < 8; k++) s += __expf(lg[k] - b0);
    float lse = b0 + __logf(s);
    float z = lse * lse;
    float q1 = __expf(b1 - b0);
    float r0 = 1.0f / (1.0f + q1);
    route_e[t * 2 + 0] = e0; route_e[t * 2 + 1] = e1;
    route_p[t * 2 + 0] = r0; route_p[t * 2 + 1] = q1 / (1.0f + q1);
    atomicAdd(&counts[e0], 1); atomicAdd(&counts[e1], 1);
    for (int off = 16; off; off >>= 1) z += __shfl_down(z, off, 32);
    if (tid == 0) atomicAdd(zsum, z);
  }
}

// ---------- scan: offsets, cursors, 256-row tile table, z finalize ----------
__global__ void k_scan(int* __restrict__ counts, int* __restrict__ offs,
                       int* __restrict__ cursors, int* __restrict__ ntiles,
                       int* __restrict__ tile_e, int* __restrict__ tile_r0,
                       const float* __restrict__ zsum, float* __restrict__ zout) {
  int o = 0, nt = 0;
  offs[0] = 0;
  for (int e = 0; e < 8; e++) {
    int c = counts[e];
    cursors[e] = o;
    for (int r = 0; r < c; r += 256) { tile_e[nt] = e; tile_r0[nt] = o + r; nt++; }
    o += c;
    offs[e + 1] = o;
  }
  *ntiles = nt;
  *zout = *zsum * (0.001f / 8192.0f);
}

// ---------- scatter with per-wave aggregated atomics ----------
__global__ __launch_bounds__(256) void k_scatter(const int* __restrict__ route_e,
                                                 int* __restrict__ cursors,
                                                 int* __restrict__ seg) {
  int i = blockIdx.x * 256 + threadIdx.x;   // < 16384
  int e = route_e[i];
  int lane = threadIdx.x & 63;
#pragma unroll
  for (int ex = 0; ex < 8; ex++) {
    unsigned long long mask = __ballot(e == ex);
    if (e == ex) {
      int cnt = __popcll(mask);
      int leader = __ffsll((long long)mask) - 1;
      int base = 0;
      if (lane == leader) base = atomicAdd(&cursors[ex], cnt);
      base = __shfl(base, leader, 64);
      int rank = __popcll(mask & ((1ull << lane) - 1ull));
      seg[base + rank] = i;
    }
  }
}

// ============ 256x256x64 counted-vmcnt pipelined GEMMs (T4 + T5) ============
// 512 threads = 8 waves (2 M x 4 N); per-wave 128x64 out; LDS 128 KiB.
// Raw s_barrier (no implicit vmcnt(0) drain); stage kt+2 into buf[kt&1] after
// the barrier ending its reads; vmcnt(8) waits only the 1-iteration-old loads.

#define BAR()    asm volatile("s_barrier" ::: "memory")
#define WAITV8() asm volatile("s_waitcnt vmcnt(8)" ::: "memory")
#define WAITV0() asm volatile("s_waitcnt vmcnt(0)" ::: "memory")

#define GSTAGE(AS, BS, B, KT)                                          \
  do {                                                                 \
    async_cp16(asrc[0] + (KT) * 64, &AS[B][(w * 4 + 0) * 512]);        \
    async_cp16(bsrc[0] + (KT) * 64, &BS[B][(w * 4 + 0) * 512]);        \
    async_cp16(asrc[1] + (KT) * 64, &AS[B][(w * 4 + 1) * 512]);        \
    async_cp16(bsrc[1] + (KT) * 64, &BS[B][(w * 4 + 1) * 512]);        \
    async_cp16(asrc[2] + (KT) * 64, &AS[B][(w * 4 + 2) * 512]);        \
    async_cp16(bsrc[2] + (KT) * 64, &BS[B][(w * 4 + 2) * 512]);        \
    async_cp16(asrc[3] + (KT) * 64, &AS[B][(w * 4 + 3) * 512]);        \
    async_cp16(bsrc[3] + (KT) * 64, &BS[B][(w * 4 + 3) * 512]);        \
  } while (0)

#define GEMM_BODY(AS, BS)                                                          \
  GSTAGE(AS, BS, 0, 0);                                                            \
  GSTAGE(AS, BS, 1, 1);                                                            \
  WAITV8(); BAR();                                                                 \
  _Pragma("unroll 2")                                                              \
  for (int kt = 0; kt < 16; kt++) {                                                \
    int cur = kt & 1;                                                              \
    _Pragma("unroll")                                                              \
    for (int kk = 0; kk < 2; kk++) {                                               \
      int kc = kk * 4 + (l >> 4);                                                  \
      int c = (kc ^ (rl & 7)) * 8;                                                 \
      bf16x8 bfr[4], af[8];                                                        \
      _Pragma("unroll")                                                            \
      for (int n = 0; n < 4; n++)                                                  \
        bfr[n] = *(const bf16x8*)&BS[cur][(wc * 64 + n * 16 + rl) * 64 + c];       \
      _Pragma("unroll")                                                            \
      for (int m = 0; m < 8; m++)                                                  \
        af[m] = *(const bf16x8*)&AS[cur][(wr * 128 + m * 16 + rl) * 64 + c];       \
      __builtin_amdgcn_s_setprio(1);                                               \
      _Pragma("unroll")                                                            \
      for (int m = 0; m < 8; m++)                                                  \
        _Pragma("unroll")                                                          \
        for (int n = 0; n < 4; n++)                                                \
          acc[m][n] = __builtin_amdgcn_mfma_f32_16x16x32_bf16(af[m], bfr[n],       \
                                                              acc[m][n], 0, 0, 0); \
      __builtin_amdgcn_s_setprio(0);                                               \
    }                                                                              \
    BAR();                                                                         \
    if (kt < 14) { GSTAGE(AS, BS, cur, kt + 2); WAITV8(); }                        \
    else         { WAITV0(); }                                                     \
    BAR();                                                                         \
  }

// ---------- GEMM1: H = gelu(gather(x) @ wi + bi), bf16 out ----------
__global__ __launch_bounds__(512, 2) void k_gemm_h(
    const u16* __restrict__ xb, const u16* __restrict__ wit, const float* __restrict__ wib,
    u16* __restrict__ hb, const int* __restrict__ seg, const int* __restrict__ offs,
    const int* __restrict__ tile_e, const int* __restrict__ tile_r0,
    const int* __restrict__ ntiles) {
  __shared__ u16 As[2][256 * 64];
  __shared__ u16 Bs[2][256 * 64];
  int bid = blockIdx.x;                         // 288 blocks, XCD-chunked swizzle
  int swz = (bid & 7) * 36 + (bid >> 3);
  int mt = swz >> 2;
  if (mt >= *ntiles) return;
  int n0 = (swz & 3) << 8;
  int e = tile_e[mt], r0 = tile_r0[mt], end = offs[e + 1];
  int tid = threadIdx.x;
  int w = tid >> 6, l = tid & 63;
  int lr = l >> 3, lc = l & 7;
  int cs = lc ^ lr;                             // pre-swizzled source chunk (T2)
  const u16* asrc[4];
  const u16* bsrc[4];
#pragma unroll
  for (int j = 0; j < 4; j++) {
    int r = (w * 4 + j) * 8 + lr;               // 0..255
    int gr = r0 + r;
    int idx = seg[(gr < end) ? gr : r0];
    asrc[j] = xb + (size_t)(idx >> 1) * 1024 + cs * 8;
    bsrc[j] = wit + ((size_t)e << 20) + (size_t)(n0 + r) * 1024 + cs * 8;
  }
  f32x4 acc[8][4];
  f32x4 z4 = {0.f, 0.f, 0.f, 0.f};
#pragma unroll
  for (int m = 0; m < 8; m++)
#pragma unroll
    for (int n = 0; n < 4; n++) acc[m][n] = z4;
  int wr = w >> 2, wc = w & 3;
  int rl = l & 15;
  GEMM_BODY(As, Bs)
  int rh = l >> 4;
#pragma unroll
  for (int n = 0; n < 4; n++) {
    int col = n0 + wc * 64 + n * 16 + rl;
    float bias = wib[e * 1024 + col];
#pragma unroll
    for (int m = 0; m < 8; m++) {
      int rbase = r0 + wr * 128 + m * 16 + rh * 4;
#pragma unroll
      for (int j = 0; j < 4; j++) {
        int gr = rbase + j;
        if (gr < end)
          hb[(size_t)gr * 1024 + col] = f2b(gelu_f(acc[m][n][j] + bias));
      }
    }
  }
}

// ---------- GEMM2: out[idx] = (H @ wo + bo) * p, scattered ----------
__global__ __launch_bounds__(512, 2) void k_gemm_o(
    const u16* __restrict__ hb, const u16* __restrict__ wot, const float* __restrict__ wob,
    float* __restrict__ out, const int* __restrict__ seg, const int* __restrict__ offs,
    const int* __restrict__ tile_e, const int* __restrict__ tile_r0,
    const int* __restrict__ ntiles, const float* __restrict__ route_p) {
  __shared__ u16 As[2][256 * 64];
  __shared__ u16 Bs[2][256 * 64];
  int bid = blockIdx.x;
  int swz = (bid & 7) * 36 + (bid >> 3);
  int mt = swz >> 2;
  if (mt >= *ntiles) return;
  int n0 = (swz & 3) << 8;
  int e = tile_e[mt], r0 = tile_r0[mt], end = offs[e + 1];
  int tid = threadIdx.x;
  int w = tid >> 6, l = tid & 63;
  int lr = l >> 3, lc = l & 7;
  int cs = lc ^ lr;
  const u16* asrc[4];
  const u16* bsrc[4];
#pragma unroll
  for (int j = 0; j < 4; j++) {
    int r = (w * 4 + j) * 8 + lr;
    int gr = r0 + r;
    int grc = (gr < end) ? gr : r0;
    asrc[j] = hb + (size_t)grc * 1024 + cs * 8;   // H is segment-ordered: contiguous
    bsrc[j] = wot + ((size_t)e << 20) + (size_t)(n0 + r) * 1024 + cs * 8;
  }
  f32x4 acc[8][4];
  f32x4 z4 = {0.f, 0.f, 0.f, 0.f};
#pragma unroll
  for (int m = 0; m < 8; m++)
#pragma unroll
    for (int n = 0; n < 4; n++) acc[m][n] = z4;
  int wr = w >> 2, wc = w & 3;
  int rl = l & 15;
  GEMM_BODY(As, Bs)
  int rh = l >> 4;
#pragma unroll
  for (int m = 0; m < 8; m++) {
    int rbase = r0 + wr * 128 + m * 16 + rh * 4;
#pragma unroll
    for (int j = 0; j < 4; j++) {
      int gr = rbase + j;
      if (gr >= end) continue;
      int idx = seg[gr];
      float p = route_p[idx];
      float* orow = out + (size_t)idx * 1024;
#pragma unroll
      for (int n = 0; n < 4; n++) {
        int col = n0 + wc * 64 + n * 16 + rl;
        orow[col] = (acc[m][n][j] + wob[e * 1024 + col]) * p;
      }
    }
  }
}

extern "C" void kernel_launch(void* const* d_in, const int* in_sizes, int n_in,
                              void* d_out, int out_size, void* d_ws, size_t ws_size,
                              hipStream_t stream) {
  if (ws_size < WS_NEED) return;
  const float* x   = (const float*)d_in[0];
  const float* rw  = (const float*)d_in[1];
  const float* rb  = (const float*)d_in[2];
  const float* wiw = (const float*)d_in[3];
  const float* wib = (const float*)d_in[4];
  const float* wow = (const float*)d_in[5];
  const float* wob = (const float*)d_in[6];
  float* out = (float*)d_out;
  char* ws = (char*)d_ws;

  u16*   xb      = (u16*)(ws + XB_OFF);
  u16*   wit     = (u16*)(ws + WIT_OFF);
  u16*   wot     = (u16*)(ws + WOT_OFF);
  u16*   hb      = (u16*)(ws + HB_OFF);
  int*   route_e = (int*)(ws + RE_OFF);
  float* route_p = (float*)(ws + RP_OFF);
  int*   seg     = (int*)(ws + SEG_OFF);
  int*   counts  = (int*)(ws + META_OFF + 0);
  int*   offs    = (int*)(ws + META_OFF + 64);
  int*   cursors = (int*)(ws + META_OFF + 128);
  int*   ntiles  = (int*)(ws + META_OFF + 192);
  float* zsum    = (float*)(ws + META_OFF + 196);
  int*   tile_e  = (int*)(ws + META_OFF + 256);
  int*   tile_r0 = (int*)(ws + META_OFF + 1024);

  hipMemsetAsync(ws + META_OFF, 0, 256, stream);
  k_transpose<<<dim3(16, 16, 16), 256, 0, stream>>>(wiw, wow, wit, wot);
  k_router<<<256, 256, 0, stream>>>(x, rw, rb, xb, route_e, route_p, counts, zsum);
  k_scan<<<1, 1, 0, stream>>>(counts, offs, cursors, ntiles, tile_e, tile_r0,
                              zsum, out + (out_size - 1));
  k_scatter<<<64, 256, 0, stream>>>(route_e, cursors, seg);
  k_gemm_h<<<288, 512, 0, stream>>>(xb, wit, wib, hb, seg, offs,
                                    tile_e, tile_r0, ntiles);
  k_gemm_o<<<288, 512, 0, stream>>>(hb, wot, wob, out, seg, offs,
                                    tile_e, tile_r0, ntiles, route_p);
}

// Round 4
// 270.509 us; speedup vs baseline: 1.2748x; 1.2748x over previous
//
#include <hip/hip_runtime.h>

typedef unsigned short u16;
typedef unsigned int   u32;
typedef __bf16 bf16x8 __attribute__((ext_vector_type(8)));
typedef float  f32x4  __attribute__((ext_vector_type(4)));

#define NTOK   8192
#define NSLOT  16384

// ---- workspace layout (bytes) ----
#define XB_OFF   0UL           // x as bf16 [8192][1024]            16 MB
#define WIT_OFF  16777216UL    // wi^T bf16 [8][1024 d][1024 h]     16 MB
#define WOT_OFF  33554432UL    // wo^T bf16 [8][1024 o][1024 d]     16 MB
#define HB_OFF   50331648UL    // H bf16 [16384][1024]              32 MB
#define RE_OFF   83886080UL    // route_e int[16384]
#define RP_OFF   83951616UL    // route_p float[16384]
#define SEG_OFF  84017152UL    // seg int[16384]
#define META_OFF 84082688UL
// META: counts[8]@0, offs[9]@64, cursors[8]@128, ntiles@192, zsum@196,
//       tile_e[64]@256, tile_r0[64]@1024
#define WS_NEED  (META_OFF + 2048UL)

__device__ __forceinline__ u16 f2b(float f) {
  u32 u = __float_as_uint(f);
  u32 r = (u + 0x7fffu + ((u >> 16) & 1u)) >> 16;   // RNE
  return (u16)r;
}

__device__ __forceinline__ void async_cp16(const void* g, void* l) {
  __builtin_amdgcn_global_load_lds(
      (const __attribute__((address_space(1))) u32*)g,
      (__attribute__((address_space(3))) u32*)l, 16, 0, 0);
}

__device__ __forceinline__ float gelu_f(float v) {
  float u  = 0.7978845608028654f * (v + 0.044715f * v * v * v);
  float ex = __expf(2.0f * u);
  float th = 1.0f - 2.0f / (ex + 1.0f);
  return 0.5f * v * (1.0f + th);
}

// ---------- transpose fp32 [1024][1024] -> bf16 ^T, both weight tensors ----------
__global__ __launch_bounds__(256) void k_transpose(const float* __restrict__ wi,
                                                   const float* __restrict__ wo,
                                                   u16* __restrict__ wit,
                                                   u16* __restrict__ wot) {
  __shared__ float t[64][65];
  int z = blockIdx.z;
  int e = z & 7;
  const float* src = ((z < 8) ? wi : wo) + ((size_t)e << 20);
  u16* dst = ((z < 8) ? wit : wot) + ((size_t)e << 20);
  int h0 = blockIdx.y * 64, d0 = blockIdx.x * 64;
  int tid = threadIdx.x;
#pragma unroll
  for (int j = 0; j < 4; j++) {
    int f = tid + 256 * j;
    int r = f >> 4, c4 = f & 15;
    float4 v = *(const float4*)&src[(size_t)(h0 + r) * 1024 + d0 + c4 * 4];
    t[r][c4 * 4 + 0] = v.x; t[r][c4 * 4 + 1] = v.y;
    t[r][c4 * 4 + 2] = v.z; t[r][c4 * 4 + 3] = v.w;
  }
  __syncthreads();
#pragma unroll
  for (int j = 0; j < 4; j++) {
    int f = tid + 256 * j;
    int d = f >> 4, c4 = f & 15;
    u32 p0 = (u32)f2b(t[c4 * 4 + 0][d]) | ((u32)f2b(t[c4 * 4 + 1][d]) << 16);
    u32 p1 = (u32)f2b(t[c4 * 4 + 2][d]) | ((u32)f2b(t[c4 * 4 + 3][d]) << 16);
    u32* dp = (u32*)&dst[(size_t)(d0 + d) * 1024 + h0 + c4 * 4];
    dp[0] = p0; dp[1] = p1;
  }
}

// ---------- router: logits, softmax, top2, z-loss, counts; also emits xb ----------
__global__ __launch_bounds__(256) void k_router(const float* __restrict__ x,
    const float* __restrict__ rw, const float* __restrict__ rb,
    u16* __restrict__ xb, int* __restrict__ route_e, float* __restrict__ route_p,
    int* __restrict__ counts, float* __restrict__ zsum) {
  __shared__ float lx[32][257];
  __shared__ float lrw[1024 * 9];
  __shared__ float llog[32 * 9];
  int tid = threadIdx.x;
  int t0  = blockIdx.x * 32;
#pragma unroll
  for (int j = 0; j < 8; j++) {
    int f = tid + 256 * j;
    int h = f >> 1, half = f & 1;
    float4 v = *(const float4*)&rw[h * 8 + half * 4];
    lrw[h * 9 + half * 4 + 0] = v.x; lrw[h * 9 + half * 4 + 1] = v.y;
    lrw[h * 9 + half * 4 + 2] = v.z; lrw[h * 9 + half * 4 + 3] = v.w;
  }
  int tl = tid & 31, e = tid >> 5;
  float acc = rb[e];
  for (int ch = 0; ch < 4; ch++) {
    __syncthreads();
#pragma unroll
    for (int j = 0; j < 8; j++) {
      int f = tid + 256 * j;
      int r = f >> 6, c4 = f & 63;
      float4 v = *(const float4*)&x[(size_t)(t0 + r) * 1024 + ch * 256 + c4 * 4];
      lx[r][c4 * 4 + 0] = v.x; lx[r][c4 * 4 + 1] = v.y;
      lx[r][c4 * 4 + 2] = v.z; lx[r][c4 * 4 + 3] = v.w;
    }
    __syncthreads();
    for (int hl = 0; hl < 256; hl++)
      acc += lx[tl][hl] * lrw[(ch * 256 + hl) * 9 + e];
#pragma unroll
    for (int j = 0; j < 16; j++) {
      int f = tid + 256 * j;
      int r = f >> 7, cp = f & 127;
      u32 pk = (u32)f2b(lx[r][cp * 2]) | ((u32)f2b(lx[r][cp * 2 + 1]) << 16);
      *(u32*)&xb[(size_t)(t0 + r) * 1024 + ch * 256 + cp * 2] = pk;
    }
  }
  llog[tl * 9 + e] = acc;
  __syncthreads();
  if (tid < 32) {
    int t = t0 + tid;
    float lg[8];
#pragma unroll
    for (int k = 0; k < 8; k++) lg[k] = llog[tid * 9 + k];
    int e0 = 0; float b0 = lg[0];
#pragma unroll
    for (int k = 1; k < 8; k++) if (lg[k] > b0) { b0 = lg[k]; e0 = k; }
    int e1 = -1; float b1 = -3.4e38f;
#pragma unroll
    for (int k = 0; k < 8; k++) { if (k == e0) continue; if (lg[k] > b1) { b1 = lg[k]; e1 = k; } }
    float s = 0.f;
#pragma unroll
    for (int k = 0; k < 8; k++) s += __expf(lg[k] - b0);
    float lse = b0 + __logf(s);
    float z = lse * lse;
    float q1 = __expf(b1 - b0);
    float r0 = 1.0f / (1.0f + q1);
    route_e[t * 2 + 0] = e0; route_e[t * 2 + 1] = e1;
    route_p[t * 2 + 0] = r0; route_p[t * 2 + 1] = q1 / (1.0f + q1);
    atomicAdd(&counts[e0], 1); atomicAdd(&counts[e1], 1);
    for (int off = 16; off; off >>= 1) z += __shfl_down(z, off, 32);
    if (tid == 0) atomicAdd(zsum, z);
  }
}

// ---------- scan: offsets, cursors, 320-row tile table, z finalize ----------
__global__ void k_scan(int* __restrict__ counts, int* __restrict__ offs,
                       int* __restrict__ cursors, int* __restrict__ ntiles,
                       int* __restrict__ tile_e, int* __restrict__ tile_r0,
                       const float* __restrict__ zsum, float* __restrict__ zout) {
  int o = 0, nt = 0;
  offs[0] = 0;
  for (int e = 0; e < 8; e++) {
    int c = counts[e];
    cursors[e] = o;
    for (int r = 0; r < c; r += 320) { tile_e[nt] = e; tile_r0[nt] = o + r; nt++; }
    o += c;
    offs[e + 1] = o;
  }
  *ntiles = nt;   // <= 59 always
  *zout = *zsum * (0.001f / 8192.0f);
}

// ---------- scatter with per-wave aggregated atomics ----------
__global__ __launch_bounds__(256) void k_scatter(const int* __restrict__ route_e,
                                                 int* __restrict__ cursors,
                                                 int* __restrict__ seg) {
  int i = blockIdx.x * 256 + threadIdx.x;   // < 16384
  int e = route_e[i];
  int lane = threadIdx.x & 63;
#pragma unroll
  for (int ex = 0; ex < 8; ex++) {
    unsigned long long mask = __ballot(e == ex);
    if (e == ex) {
      int cnt = __popcll(mask);
      int leader = __ffsll((long long)mask) - 1;
      int base = 0;
      if (lane == leader) base = atomicAdd(&cursors[ex], cnt);
      base = __shfl(base, leader, 64);
      int rank = __popcll(mask & ((1ull << lane) - 1ull));
      seg[base + rank] = i;
    }
  }
}

// ============ 320x256x64 grouped GEMM, 5-phase interleave (T3+T4+T5) ============
// 512 threads = 8 waves (2M x 4N); per-wave 160x64 out (10x4 frags).
// LDS: A dbuf 80 KiB + B dbuf 64 KiB = 144 KiB -> 1 block/CU, 2 waves/SIMD.
// Per K-tile: 5 phases x {stage-slice, ds_read quintant, raw barrier, MFMA x16}.
// Tile g+1 staged (phases 0-1) into buf (g+1)&1, freed at group g-1's last barrier.
// Single vmcnt(0) at phase-4 end: youngest stage is >=3 phases (~1800 cy) old.

#define BAR()    asm volatile("s_barrier" ::: "memory")
#define WAITV0() asm volatile("s_waitcnt vmcnt(0)" ::: "memory")

#define STAGE_A(B, KT, J) async_cp16(asrc[J] + (KT) * 64, &As[B][(w * 40 + (J) * 8) * 64])
#define STAGE_B(B, KT, J) async_cp16(bsrc[J] + (KT) * 64, &Bs[B][(w * 32 + (J) * 8) * 64])

#define PHASE(CUR, Q)                                                              \
  do {                                                                             \
    bf16x8 af[2][2], bfr[2][4];                                                    \
    _Pragma("unroll")                                                              \
    for (int kk = 0; kk < 2; kk++) {                                               \
      int c = ((kk * 4 + rh) ^ (rl & 7)) * 8;                                      \
      _Pragma("unroll")                                                            \
      for (int d = 0; d < 2; d++)                                                  \
        af[kk][d] = *(const bf16x8*)&As[CUR][(wr * 160 + (2 * (Q) + d) * 16 + rl) * 64 + c]; \
      _Pragma("unroll")                                                            \
      for (int n = 0; n < 4; n++)                                                  \
        bfr[kk][n] = *(const bf16x8*)&Bs[CUR][(wc * 64 + n * 16 + rl) * 64 + c];   \
    }                                                                              \
    __builtin_amdgcn_s_setprio(1);                                                 \
    _Pragma("unroll")                                                              \
    for (int kk = 0; kk < 2; kk++)                                                 \
      _Pragma("unroll")                                                            \
      for (int d = 0; d < 2; d++)                                                  \
        _Pragma("unroll")                                                          \
        for (int n = 0; n < 4; n++)                                                \
          acc[2 * (Q) + d][n] = __builtin_amdgcn_mfma_f32_16x16x32_bf16(           \
              af[kk][d], bfr[kk][n], acc[2 * (Q) + d][n], 0, 0, 0);                \
    __builtin_amdgcn_s_setprio(0);                                                 \
  } while (0)

#define GEMM_BODY()                                                                \
  _Pragma("unroll")                                                                \
  for (int j = 0; j < 5; j++) STAGE_A(0, 0, j);                                    \
  _Pragma("unroll")                                                                \
  for (int j = 0; j < 4; j++) STAGE_B(0, 0, j);                                    \
  WAITV0(); BAR();                                                                 \
  _Pragma("unroll 2")                                                              \
  for (int g = 0; g < 16; g++) {                                                   \
    int cur = g & 1, nxt = cur ^ 1;                                                \
    bool pf = (g < 15);                                                            \
    if (pf) { STAGE_A(nxt, g + 1, 0); STAGE_A(nxt, g + 1, 1); STAGE_A(nxt, g + 1, 2); \
              STAGE_B(nxt, g + 1, 0); STAGE_B(nxt, g + 1, 1); }                    \
    PHASE(cur, 0); BAR();                                                          \
    if (pf) { STAGE_A(nxt, g + 1, 3); STAGE_A(nxt, g + 1, 4);                      \
              STAGE_B(nxt, g + 1, 2); STAGE_B(nxt, g + 1, 3); }                    \
    PHASE(cur, 1); BAR();                                                          \
    PHASE(cur, 2); BAR();                                                          \
    PHASE(cur, 3); BAR();                                                          \
    PHASE(cur, 4);                                                                 \
    WAITV0(); BAR();                                                               \
  }

// ---------- GEMM1: H = gelu(gather(x) @ wi + bi), bf16 out ----------
__global__ __launch_bounds__(512, 2) void k_gemm_h(
    const u16* __restrict__ xb, const u16* __restrict__ wit, const float* __restrict__ wib,
    u16* __restrict__ hb, const int* __restrict__ seg, const int* __restrict__ offs,
    const int* __restrict__ tile_e, const int* __restrict__ tile_r0,
    const int* __restrict__ ntiles) {
  __shared__ u16 As[2][320 * 64];
  __shared__ u16 Bs[2][256 * 64];
  int bid = blockIdx.x;                         // 240 blocks, XCD-chunked swizzle
  int swz = (bid & 7) * 30 + (bid >> 3);
  int mt = swz >> 2;
  if (mt >= *ntiles) return;
  int n0 = (swz & 3) << 8;
  int e = tile_e[mt], r0 = tile_r0[mt], end = offs[e + 1];
  int tid = threadIdx.x;
  int w = tid >> 6, l = tid & 63;
  int lr = l >> 3, lc = l & 7;
  int cs = lc ^ lr;                             // pre-swizzled source chunk (T2)
  const u16* asrc[5];
  const u16* bsrc[4];
#pragma unroll
  for (int j = 0; j < 5; j++) {
    int gr = r0 + w * 40 + j * 8 + lr;
    int idx = seg[(gr < end) ? gr : r0];
    asrc[j] = xb + (size_t)(idx >> 1) * 1024 + cs * 8;
  }
#pragma unroll
  for (int j = 0; j < 4; j++)
    bsrc[j] = wit + ((size_t)e << 20) + (size_t)(n0 + w * 32 + j * 8 + lr) * 1024 + cs * 8;
  f32x4 acc[10][4];
  f32x4 z4 = {0.f, 0.f, 0.f, 0.f};
#pragma unroll
  for (int m = 0; m < 10; m++)
#pragma unroll
    for (int n = 0; n < 4; n++) acc[m][n] = z4;
  int wr = w >> 2, wc = w & 3;
  int rl = l & 15, rh = l >> 4;
  GEMM_BODY()
#pragma unroll
  for (int n = 0; n < 4; n++) {
    int col = n0 + wc * 64 + n * 16 + rl;
    float bias = wib[e * 1024 + col];
#pragma unroll
    for (int m = 0; m < 10; m++) {
      int rbase = r0 + wr * 160 + m * 16 + rh * 4;
#pragma unroll
      for (int j = 0; j < 4; j++) {
        int gr = rbase + j;
        if (gr < end)
          hb[(size_t)gr * 1024 + col] = f2b(gelu_f(acc[m][n][j] + bias));
      }
    }
  }
}

// ---------- GEMM2: out[idx] = (H @ wo + bo) * p, scattered ----------
__global__ __launch_bounds__(512, 2) void k_gemm_o(
    const u16* __restrict__ hb, const u16* __restrict__ wot, const float* __restrict__ wob,
    float* __restrict__ out, const int* __restrict__ seg, const int* __restrict__ offs,
    const int* __restrict__ tile_e, const int* __restrict__ tile_r0,
    const int* __restrict__ ntiles, const float* __restrict__ route_p) {
  __shared__ u16 As[2][320 * 64];
  __shared__ u16 Bs[2][256 * 64];
  int bid = blockIdx.x;
  int swz = (bid & 7) * 30 + (bid >> 3);
  int mt = swz >> 2;
  if (mt >= *ntiles) return;
  int n0 = (swz & 3) << 8;
  int e = tile_e[mt], r0 = tile_r0[mt], end = offs[e + 1];
  int tid = threadIdx.x;
  int w = tid >> 6, l = tid & 63;
  int lr = l >> 3, lc = l & 7;
  int cs = lc ^ lr;
  const u16* asrc[5];
  const u16* bsrc[4];
#pragma unroll
  for (int j = 0; j < 5; j++) {
    int gr = r0 + w * 40 + j * 8 + lr;
    int grc = (gr < end) ? gr : r0;
    asrc[j] = hb + (size_t)grc * 1024 + cs * 8;   // H is segment-ordered: contiguous
  }
#pragma unroll
  for (int j = 0; j < 4; j++)
    bsrc[j] = wot + ((size_t)e << 20) + (size_t)(n0 + w * 32 + j * 8 + lr) * 1024 + cs * 8;
  f32x4 acc[10][4];
  f32x4 z4 = {0.f, 0.f, 0.f, 0.f};
#pragma unroll
  for (int m = 0; m < 10; m++)
#pragma unroll
    for (int n = 0; n < 4; n++) acc[m][n] = z4;
  int wr = w >> 2, wc = w & 3;
  int rl = l & 15, rh = l >> 4;
  GEMM_BODY()
#pragma unroll
  for (int m = 0; m < 10; m++) {
    int rbase = r0 + wr * 160 + m * 16 + rh * 4;
#pragma unroll
    for (int j = 0; j < 4; j++) {
      int gr = rbase + j;
      if (gr >= end) continue;
      int idx = seg[gr];
      float p = route_p[idx];
      float* orow = out + (size_t)idx * 1024;
#pragma unroll
      for (int n = 0; n < 4; n++) {
        int col = n0 + wc * 64 + n * 16 + rl;
        orow[col] = (acc[m][n][j] + wob[e * 1024 + col]) * p;
      }
    }
  }
}

extern "C" void kernel_launch(void* const* d_in, const int* in_sizes, int n_in,
                              void* d_out, int out_size, void* d_ws, size_t ws_size,
                              hipStream_t stream) {
  if (ws_size < WS_NEED) return;
  const float* x   = (const float*)d_in[0];
  const float* rw  = (const float*)d_in[1];
  const float* rb  = (const float*)d_in[2];
  const float* wiw = (const float*)d_in[3];
  const float* wib = (const float*)d_in[4];
  const float* wow = (const float*)d_in[5];
  const float* wob = (const float*)d_in[6];
  float* out = (float*)d_out;
  char* ws = (char*)d_ws;

  u16*   xb      = (u16*)(ws + XB_OFF);
  u16*   wit     = (u16*)(ws + WIT_OFF);
  u16*   wot     = (u16*)(ws + WOT_OFF);
  u16*   hb      = (u16*)(ws + HB_OFF);
  int*   route_e = (int*)(ws + RE_OFF);
  float* route_p = (float*)(ws + RP_OFF);
  int*   seg     = (int*)(ws + SEG_OFF);
  int*   counts  = (int*)(ws + META_OFF + 0);
  int*   offs    = (int*)(ws + META_OFF + 64);
  int*   cursors = (int*)(ws + META_OFF + 128);
  int*   ntiles  = (int*)(ws + META_OFF + 192);
  float* zsum    = (float*)(ws + META_OFF + 196);
  int*   tile_e  = (int*)(ws + META_OFF + 256);
  int*   tile_r0 = (int*)(ws + META_OFF + 1024);

  hipMemsetAsync(ws + META_OFF, 0, 256, stream);
  k_transpose<<<dim3(16, 16, 16), 256, 0, stream>>>(wiw, wow, wit, wot);
  k_router<<<256, 256, 0, stream>>>(x, rw, rb, xb, route_e, route_p, counts, zsum);
  k_scan<<<1, 1, 0, stream>>>(counts, offs, cursors, ntiles, tile_e, tile_r0,
                              zsum, out + (out_size - 1));
  k_scatter<<<64, 256, 0, stream>>>(route_e, cursors, seg);
  k_gemm_h<<<240, 512, 0, stream>>>(xb, wit, wib, hb, seg, offs,
                                    tile_e, tile_r0, ntiles);
  k_gemm_o<<<240, 512, 0, stream>>>(hb, wot, wob, out, seg, offs,
                                    tile_e, tile_r0, ntiles, route_p);
}